// Round 3
// baseline (989.190 us; speedup 1.0000x reference)
//
#include <hip/hip_runtime.h>

// FlowNetC correlation, B=8 C=256 H=64 W=128, 9x9 displacement grid.
// out[b,(i+4)*9+(j+4),h,w] = (1/256) * sum_c in1[b,c,h,w]*in2[b,c,h+i,w+j]
// (in2 zero-padded by 4 in h,w).
//
// 256 blocks (b x 2-row h-tile) x 576 threads (9 waves, wave = dy).
// Lane = (q: 8 w-px, hp: h row, cs: channel half). acc[8px][9dx]/lane.
// R3: XCD swizzle (batch b -> XCD b, so dy-overlap in2 re-reads hit XCD L2);
// triple-buffered LDS staged 2 phases ahead with counted vmcnt(20) so a full
// phase of staging stays in flight across every barrier (duty-cycle fix for
// R2's 1.1 TB/s effective BW); v1 double-buffered A/B, issued at phase top.
// Boundary h-tiles (uneven staging count) drain vmcnt(0) -- they block nobody.

#define AS1 __attribute__((address_space(1)))
#define AS3 __attribute__((address_space(3)))

namespace {

constexpr int Cc = 256, Hh = 64, Ww = 128;
constexpr int HW = Hh * Ww;            // 8192
constexpr int ND = 81;
constexpr int RSTRIDE = 136;           // 4 zero | 64 even-chunk | 64 odd-chunk | 4 zero
constexpr int CHSTR = 10 * RSTRIDE;    // 1360 floats per (unit, cs-half)
constexpr int UNITSTR = 2 * CHSTR;     // 2720 floats per channel-unit
constexpr int KC = 4;                  // channel-units per phase
constexpr int BUFSTR = KC * UNITSTR;   // 10880 floats = 43520 B
constexpr int NPH = 128 / KC;          // 32 phases

__device__ __forceinline__ void async4(const float* g, float* l) {
  __builtin_amdgcn_global_load_lds((const AS1 unsigned int*)(g),
                                   (AS3 unsigned int*)(l), 4, 0, 0);
}

__global__ __launch_bounds__(576) void corr_kernel(
    const float* __restrict__ in1, const float* __restrict__ in2,
    float* __restrict__ out) {
  __shared__ __align__(16) float lds[3 * BUFSTR];  // 130560 B

  const int tid = threadIdx.x;
  const int dyw = tid >> 6;          // wave id = dy 0..8
  const int lane = tid & 63;
  const int q = lane & 15;           // 8 w-pixels: w = 8q..8q+7
  const int hp = (lane >> 4) & 1;    // h row within tile
  const int cs = lane >> 5;          // channel half

  // XCD swizzle: dispatch i -> XCD i%8. Map so batch b lives on XCD b:
  // all in2[b] dy-overlap re-reads then hit that XCD's L2.
  const int bid0 = blockIdx.x;
  const int nb = (bid0 & 7) * 32 + (bid0 >> 3);
  const int b = nb >> 5;
  const int h0 = (nb & 31) << 1;
  const bool bdry = (h0 < 4) || (h0 > 58);  // uneven staging count

  // zero the pad slots (0..3, 132..135 of each row) in all 3 buffers; never
  // overwritten by staging (staging writes slots 4..131 only)
  for (int s = tid; s < 1920; s += 576) {
    int sl = s & 7; int t2 = s >> 3;
    int row = t2 % 10; t2 /= 10;
    int csx = t2 & 1; t2 >>= 1;
    int unit = t2 & 3; int buf = t2 >> 2;
    lds[buf * BUFSTR + unit * UNITSTR + csx * CHSTR + row * RSTRIDE +
        (sl < 4 ? sl : 128 + sl)] = 0.0f;
  }
  __syncthreads();

  // staging: 40 wave-loads per channel-unit (2 cs x 10 rows x 2 row-halves),
  // 5 per wave (wave 8 duplicates 5 of wave 0's benignly).
  // Parity-deinterleaved source x so b128 window reads are aligned:
  const int sx0 = 8 * (lane >> 2) + (lane & 3) + 4;  // x%8 in 4..7 -> phys 4+l
  const int sx1 = sx0 - 4;                           // x%8 in 0..3 -> phys 68+l
  const size_t in2_b = (size_t)b * Cc * HW;

  int ldsoff[5]; int goff[5]; bool gval[5];
#pragma unroll
  for (int k = 0; k < 5; ++k) {
    int u = dyw * 5 + k; if (u >= 40) u -= 40;
    int cs_u = u / 20; int rem = u - cs_u * 20;
    int rr = rem >> 1; int half = rem & 1;
    int grow = h0 - 4 + rr;
    ldsoff[k] = cs_u * CHSTR + rr * RSTRIDE + 4 + 64 * half;
    goff[k] = cs_u * 128 * HW + grow * Ww + (half ? sx1 : sx0);
    gval[k] = (unsigned)grow < (unsigned)Hh;
  }

  auto stage = [&](int j, int buf) {  // channel-unit j -> LDS buffer buf
    const int lb = buf * BUFSTR + (j & 3) * UNITSTR;
    const float* in2j = in2 + in2_b + (size_t)j * HW;
#pragma unroll
    for (int k = 0; k < 5; ++k) {
      float* ldst = &lds[lb + ldsoff[k]];
      if (gval[k]) async4(in2j + goff[k], ldst);
      else         ldst[lane] = 0.0f;
    }
  };

  const int rb = cs * CHSTR + (dyw + hp) * RSTRIDE + 4 * q;
  const float* in1p =
      in1 + ((size_t)(b * Cc + cs * 128) * Hh + (h0 + hp)) * Ww + 8 * q;

  float acc[8][9];
#pragma unroll
  for (int px = 0; px < 8; ++px)
#pragma unroll
    for (int dx = 0; dx < 9; ++dx) acc[px][dx] = 0.0f;

  float v1A[4][8], v1B[4][8];

  // prologue: v1A <- phase-0 channels; stage phases 0 and 1
#pragma unroll
  for (int c = 0; c < 4; ++c) {
    const float* pp_ = in1p + (size_t)c * HW;
    float4 a = *(const float4*)pp_; float4 d = *(const float4*)(pp_ + 4);
    v1A[c][0] = a.x; v1A[c][1] = a.y; v1A[c][2] = a.z; v1A[c][3] = a.w;
    v1A[c][4] = d.x; v1A[c][5] = d.y; v1A[c][6] = d.z; v1A[c][7] = d.w;
  }
  stage(0, 0); stage(1, 0); stage(2, 0); stage(3, 0);
  stage(4, 1); stage(5, 1); stage(6, 1); stage(7, 1);
  if (!bdry) asm volatile("s_waitcnt vmcnt(20) lgkmcnt(0)" ::: "memory");
  else       asm volatile("s_waitcnt vmcnt(0) lgkmcnt(0)" ::: "memory");
  __builtin_amdgcn_s_barrier();
  __builtin_amdgcn_sched_barrier(0);

  // phase body: issue v1(p+1) then stage(p+2), compute phase p, counted drain
  auto phase = [&](int p, int bcomp, int bstage, float (&use)[4][8],
                   float (&fill)[4][8]) {
    const bool pre1 = (p + 1 < NPH);
    const bool pre2 = (p + 2 < NPH);
    if (pre1) {
#pragma unroll
      for (int c = 0; c < 4; ++c) {
        const float* pp_ = in1p + (size_t)((p + 1) * 4 + c) * HW;
        float4 a = *(const float4*)pp_; float4 d = *(const float4*)(pp_ + 4);
        fill[c][0] = a.x; fill[c][1] = a.y; fill[c][2] = a.z; fill[c][3] = a.w;
        fill[c][4] = d.x; fill[c][5] = d.y; fill[c][6] = d.z; fill[c][7] = d.w;
      }
    }
    if (pre2) {
      stage((p + 2) * 4 + 0, bstage); stage((p + 2) * 4 + 1, bstage);
      stage((p + 2) * 4 + 2, bstage); stage((p + 2) * 4 + 3, bstage);
    }
    __builtin_amdgcn_sched_barrier(0);
#pragma unroll
    for (int c = 0; c < 4; ++c) {
      const int base = bcomp * BUFSTR + c * UNITSTR + rb;
      const float4 W0 = *(const float4*)&lds[base];       // t 0..3
      const float4 Wa = *(const float4*)&lds[base + 4];   // t 8..11
      const float4 W2 = *(const float4*)&lds[base + 68];  // t 4..7
      const float4 Wb = *(const float4*)&lds[base + 72];  // t 12..15
      const float t[16] = {W0.x, W0.y, W0.z, W0.w, W2.x, W2.y, W2.z, W2.w,
                           Wa.x, Wa.y, Wa.z, Wa.w, Wb.x, Wb.y, Wb.z, Wb.w};
#pragma unroll
      for (int dx = 0; dx < 9; ++dx)
#pragma unroll
        for (int px = 0; px < 8; ++px)
          acc[px][dx] = fmaf(use[c][px], t[px + dx], acc[px][dx]);
    }
    __builtin_amdgcn_sched_barrier(0);
    // drain stage(p+1)+v1(p+1); keep stage(p+2)'s 20 loads in flight
    if (pre2 && !bdry) {
      asm volatile("s_waitcnt vmcnt(20) lgkmcnt(0)" ::: "memory");
    } else {
      asm volatile("s_waitcnt vmcnt(0) lgkmcnt(0)" ::: "memory");
    }
    __builtin_amdgcn_s_barrier();
    __builtin_amdgcn_sched_barrier(0);
  };

  int bc = 0, bs = 2;  // compute buffer = p%3, staging buffer = (p+2)%3
#pragma unroll 1
  for (int pp = 0; pp < NPH; pp += 2) {
    phase(pp, bc, bs, v1A, v1B);
    bc = (bc == 2) ? 0 : bc + 1; bs = (bs == 2) ? 0 : bs + 1;
    phase(pp + 1, bc, bs, v1B, v1A);
    bc = (bc == 2) ? 0 : bc + 1; bs = (bs == 2) ? 0 : bs + 1;
  }

  // reduce channel halves
#pragma unroll
  for (int px = 0; px < 8; ++px)
#pragma unroll
    for (int dx = 0; dx < 9; ++dx)
      acc[px][dx] += __shfl_xor(acc[px][dx], 32, 64);

  const float s = 1.0f / 256.0f;
  float* outp =
      out + (((size_t)b * ND + (size_t)dyw * 9) * Hh + (h0 + hp)) * Ww + 8 * q;
  if (cs == 0) {
#pragma unroll
    for (int dx = 0; dx < 5; ++dx) {
      float4 lo = make_float4(acc[0][dx] * s, acc[1][dx] * s, acc[2][dx] * s,
                              acc[3][dx] * s);
      float4 hi = make_float4(acc[4][dx] * s, acc[5][dx] * s, acc[6][dx] * s,
                              acc[7][dx] * s);
      *(float4*)(outp + (size_t)dx * HW) = lo;
      *(float4*)(outp + (size_t)dx * HW + 4) = hi;
    }
  } else {
#pragma unroll
    for (int dx = 4; dx < 9; ++dx) {  // dx=4 written by both halves, same value
      float4 lo = make_float4(acc[0][dx] * s, acc[1][dx] * s, acc[2][dx] * s,
                              acc[3][dx] * s);
      float4 hi = make_float4(acc[4][dx] * s, acc[5][dx] * s, acc[6][dx] * s,
                              acc[7][dx] * s);
      *(float4*)(outp + (size_t)dx * HW) = lo;
      *(float4*)(outp + (size_t)dx * HW + 4) = hi;
    }
  }
}

}  // namespace

extern "C" void kernel_launch(void* const* d_in, const int* in_sizes, int n_in,
                              void* d_out, int out_size, void* d_ws,
                              size_t ws_size, hipStream_t stream) {
  (void)in_sizes; (void)n_in; (void)out_size; (void)d_ws; (void)ws_size;
  const float* in1 = (const float*)d_in[0];
  const float* in2 = (const float*)d_in[1];
  float* outp = (float*)d_out;
  corr_kernel<<<256, 576, 0, stream>>>(in1, in2, outp);
}

// Round 4
// 92.683 us; speedup vs baseline: 10.6728x; 10.6728x over previous
//
#include <hip/hip_runtime.h>

// FlowNetC correlation, B=8 C=256 H=64 W=128, 9x9 grid.
// out[b,(dy)*9+dx,h,w] = (1/256) * sum_c in1[b,c,h,w]*in2[b,c,h+dy-4,w+dx-4]
// (in2 zero-padded by 4 in h,w).
//
// R4 redesign: block = (b,h,dy) -> needs ONE in2 row. 4608 blocks x 256 thr
// (4 waves), 4 blocks/CU. Thread = (q:16 w-octs) x (cs:16 ch-slices, cs=4w+cslo).
// Each wave stages+consumes only its own 4 channels/phase => NO barriers in
// main loop; per-wave counted vmcnt(10) (8 stage + 2 v1 loads/phase, uniform
// across all blocks). LDS rows parity-deinterleaved (conflict-free b128 window
// reads); pads zeroed once. XCD swizzle: batch b -> one XCD (9x dy-sharing of
// rows becomes L2 hits). End: shfl_xor(16,32) + one-barrier LDS reduce.
// R3 lesson: no lambdas with array-ref params (scratch spill); macros + static
// indices only.

#define AS1 __attribute__((address_space(1)))
#define AS3 __attribute__((address_space(3)))

namespace {

constexpr int Cc = 256, Hh = 64, Ww = 128;
constexpr int HW = Hh * Ww;      // 8192
constexpr int ND = 81;
constexpr int ROWF = 136;        // padded row: [4 zero|64 even-quads|64 odd-quads|4 zero]
constexpr int WBUF = 4 * ROWF;   // 544 floats: one buffer (4 ch) per wave
constexpr int WREG = 2 * WBUF;   // 1088 floats per wave (double-buffered)
constexpr int NPH = 16;          // 16 phases x 16 channels

__device__ __forceinline__ void async4(const float* g, float* l) {
  __builtin_amdgcn_global_load_lds((const AS1 unsigned int*)g,
                                   (AS3 unsigned int*)l, 4, 0, 0);
}

__global__ __launch_bounds__(256, 4) void corr_kernel(
    const float* __restrict__ in1, const float* __restrict__ in2,
    float* __restrict__ out) {
  __shared__ __align__(16) float lds[4608];  // 4x1088 staging; 4608 reduce

  const int tid = threadIdx.x;
  const int w = tid >> 6;
  const int lane = tid & 63;
  const int q = lane & 15;
  const int cslo = lane >> 4;

  // XCD swizzle: dispatch i -> XCD i%8; give XCD x the contiguous nb-chunk
  // [576x, 576x+576) = all (h,dy) blocks of batch x.
  const int bid0 = blockIdx.x;
  const int nb = (bid0 & 7) * 576 + (bid0 >> 3);
  const int b = nb / 576;
  const int rem = nb - b * 576;
  const int h = rem / 9;
  const int dy = rem - h * 9;
  const int row2 = h + dy - 4;

  float* outbase = out + (((size_t)b * ND + (size_t)dy * 9) * Hh + h) * Ww;

  if ((unsigned)row2 >= (unsigned)Hh) {  // dy shifts row out of range -> zeros
    if (tid < 144) {
      const int dx = tid >> 4, qq = tid & 15;
      const float4 z = make_float4(0.f, 0.f, 0.f, 0.f);
      *(float4*)(outbase + (size_t)dx * HW + 8 * qq) = z;
      *(float4*)(outbase + (size_t)dx * HW + 8 * qq + 4) = z;
    }
    return;
  }

  const int wb = w * WREG;
  {  // zero the 8 pad floats of each (buf, ch) row: exactly 64 per wave
    const int b2 = lane >> 5, rl = lane & 31, j = rl >> 3, p = rl & 7;
    lds[wb + b2 * WBUF + j * ROWF + (p < 4 ? p : 128 + p)] = 0.0f;
  }

  // parity-deinterleaved per-lane source x (LDS dest is linear; source is
  // pre-swizzled so b128 window reads are 16B-aligned and 2-way-free):
  const int xA = 8 * ((lane + 4) >> 2) + ((lane + 4) & 3) - 4;  // -> phys 4+lane
  const int xB = 8 * (lane >> 2) + (lane & 3);                  // -> phys 68+lane
  const float* in2row = in2 + ((size_t)b * Cc * Hh + row2) * Ww;
  const float* v1p =
      in1 + ((size_t)(b * Cc + 4 * w + cslo) * Hh + h) * Ww + 8 * q;

#define STAGE(P, BUF)                                                   \
  {                                                                     \
    const float* s0_ = in2row + (size_t)(16 * (P) + 4 * w) * HW;        \
    _Pragma("unroll") for (int j_ = 0; j_ < 4; ++j_) {                  \
      const float* src_ = s0_ + (size_t)j_ * HW;                        \
      async4(src_ + xA, &lds[wb + (BUF) * WBUF + j_ * ROWF + 4]);       \
      async4(src_ + xB, &lds[wb + (BUF) * WBUF + j_ * ROWF + 68]);      \
    }                                                                   \
  }

#define LOADV1(P, DST)                                                  \
  {                                                                     \
    const float* pp_ = v1p + (size_t)(16 * (P)) * HW;                   \
    const float4 a_ = *(const float4*)pp_;                              \
    const float4 d_ = *(const float4*)(pp_ + 4);                        \
    DST[0] = a_.x; DST[1] = a_.y; DST[2] = a_.z; DST[3] = a_.w;         \
    DST[4] = d_.x; DST[5] = d_.y; DST[6] = d_.z; DST[7] = d_.w;         \
  }

#define COMPUTE(BUF, V1)                                                 \
  {                                                                      \
    const int br_ = wb + (BUF) * WBUF + cslo * ROWF + 4 * q;             \
    const float4 A_ = *(const float4*)&lds[br_];       /* px 0..3  */    \
    const float4 B_ = *(const float4*)&lds[br_ + 68];  /* px 4..7  */    \
    const float4 C_ = *(const float4*)&lds[br_ + 4];   /* px 8..11 */    \
    const float4 D_ = *(const float4*)&lds[br_ + 72];  /* px 12..15*/    \
    const float t_[16] = {A_.x, A_.y, A_.z, A_.w, B_.x, B_.y, B_.z, B_.w,\
                          C_.x, C_.y, C_.z, C_.w, D_.x, D_.y, D_.z, D_.w};\
    _Pragma("unroll") for (int dx_ = 0; dx_ < 9; ++dx_)                  \
      _Pragma("unroll") for (int px_ = 0; px_ < 8; ++px_)                \
        acc[px_][dx_] = fmaf(V1[px_], t_[px_ + dx_], acc[px_][dx_]);     \
  }

  float acc[8][9];
#pragma unroll
  for (int px = 0; px < 8; ++px)
#pragma unroll
    for (int dx = 0; dx < 9; ++dx) acc[px][dx] = 0.0f;

  float v1a[8], v1b[8];
  STAGE(0, 0);
  LOADV1(0, v1a);

#pragma unroll 1
  for (int pp = 0; pp < NPH; pp += 2) {
    STAGE(pp + 1, 1);
    LOADV1(pp + 1, v1b);
    // drain stage(pp)+v1(pp) (oldest); keep the 10 just issued in flight
    asm volatile("s_waitcnt vmcnt(10)" ::: "memory");
    COMPUTE(0, v1a);
    if (pp + 2 < NPH) {
      STAGE(pp + 2, 0);
      LOADV1(pp + 2, v1a);
      asm volatile("s_waitcnt vmcnt(10)" ::: "memory");
    } else {
      asm volatile("s_waitcnt vmcnt(0)" ::: "memory");
    }
    COMPUTE(1, v1b);
  }

  // reduce the 4 cslo slices within each wave (lanes q, q+16, q+32, q+48)
#pragma unroll
  for (int px = 0; px < 8; ++px)
#pragma unroll
    for (int dx = 0; dx < 9; ++dx) {
      float v = acc[px][dx];
      v += __shfl_xor(v, 16, 64);
      v += __shfl_xor(v, 32, 64);
      acc[px][dx] = v;
    }

  __syncthreads();  // all waves done with staging region before overwrite
  if (cslo == 0) {  // wave partial: lds[((w*16+q)*9+dx)*8+px]
    const int pb = (w * 16 + q) * 72;
#pragma unroll
    for (int dx = 0; dx < 9; ++dx) {
      *(float4*)&lds[pb + dx * 8] =
          make_float4(acc[0][dx], acc[1][dx], acc[2][dx], acc[3][dx]);
      *(float4*)&lds[pb + dx * 8 + 4] =
          make_float4(acc[4][dx], acc[5][dx], acc[6][dx], acc[7][dx]);
    }
  }
  __syncthreads();

  if (tid < 144) {  // sum 4 wave-partials, scale, store
    const int dx = tid >> 4, qq = tid & 15;
    const float s = 1.0f / 256.0f;
    float r[8];
#pragma unroll
    for (int px = 0; px < 8; ++px) r[px] = 0.0f;
#pragma unroll
    for (int w4 = 0; w4 < 4; ++w4) {
      const int pb = ((w4 * 16 + qq) * 9 + dx) * 8;
      const float4 lo = *(const float4*)&lds[pb];
      const float4 hi = *(const float4*)&lds[pb + 4];
      r[0] += lo.x; r[1] += lo.y; r[2] += lo.z; r[3] += lo.w;
      r[4] += hi.x; r[5] += hi.y; r[6] += hi.z; r[7] += hi.w;
    }
    *(float4*)(outbase + (size_t)dx * HW + 8 * qq) =
        make_float4(r[0] * s, r[1] * s, r[2] * s, r[3] * s);
    *(float4*)(outbase + (size_t)dx * HW + 8 * qq + 4) =
        make_float4(r[4] * s, r[5] * s, r[6] * s, r[7] * s);
  }
}

}  // namespace

extern "C" void kernel_launch(void* const* d_in, const int* in_sizes, int n_in,
                              void* d_out, int out_size, void* d_ws,
                              size_t ws_size, hipStream_t stream) {
  (void)in_sizes; (void)n_in; (void)out_size; (void)d_ws; (void)ws_size;
  const float* in1 = (const float*)d_in[0];
  const float* in2 = (const float*)d_in[1];
  float* outp = (float*)d_out;
  corr_kernel<<<4608, 256, 0, stream>>>(in1, in2, outp);
}

// Round 5
// 90.143 us; speedup vs baseline: 10.9736x; 1.0282x over previous
//
#include <hip/hip_runtime.h>

// FlowNetC correlation, B=8 C=256 H=64 W=128, 9x9 grid.
// out[b,(dy)*9+dx,h,w] = (1/256) * sum_c in1[b,c,h,w]*in2[b,c,h+dy-4,w+dx-4]
// (in2 zero-padded by 4 in h,w).
//
// Block = (b,h,dy) -> needs ONE in2 row. 4608 blocks x 256 thr (4 waves).
// Thread = (q:16 w-octs) x (cs:16 ch-slices, cs=4w+cslo). Each wave stages and
// consumes only its own 4 channels/phase => NO barriers in the main loop;
// per-wave counted vmcnt(10) (8 stage + 2 v1 loads/phase, uniform across all
// blocks). LDS rows parity-deinterleaved (conflict-free b128 window reads).
// XCD swizzle: batch b -> one XCD (9x dy-sharing of rows becomes L2 hits).
// End: shfl_xor(16,32) + one-barrier LDS cross-wave reduce.
//
// R4 lesson: __launch_bounds__(256,4) caps the unified reg budget at 128 <
// ~130-reg working set -> acc partially spilled to scratch (WRITE 109 MB vs
// 21 MB output, dur 92us). (256,3) gives 170 regs -> no spill, 12 waves/CU.

#define AS1 __attribute__((address_space(1)))
#define AS3 __attribute__((address_space(3)))

namespace {

constexpr int Cc = 256, Hh = 64, Ww = 128;
constexpr int HW = Hh * Ww;      // 8192
constexpr int ND = 81;
constexpr int ROWF = 136;        // padded row: [4 zero|64 even-quads|64 odd-quads|4 zero]
constexpr int WBUF = 4 * ROWF;   // 544 floats: one buffer (4 ch) per wave
constexpr int WREG = 2 * WBUF;   // 1088 floats per wave (double-buffered)
constexpr int NPH = 16;          // 16 phases x 16 channels

__device__ __forceinline__ void async4(const float* g, float* l) {
  __builtin_amdgcn_global_load_lds((const AS1 unsigned int*)g,
                                   (AS3 unsigned int*)l, 4, 0, 0);
}

__global__ __launch_bounds__(256, 3) void corr_kernel(
    const float* __restrict__ in1, const float* __restrict__ in2,
    float* __restrict__ out) {
  __shared__ __align__(16) float lds[4608];  // 4x1088 staging; 4608 reduce

  const int tid = threadIdx.x;
  const int w = tid >> 6;
  const int lane = tid & 63;
  const int q = lane & 15;
  const int cslo = lane >> 4;

  // XCD swizzle: dispatch i -> XCD i%8; give XCD x the contiguous nb-chunk
  // [576x, 576x+576) = all (h,dy) blocks of batch x.
  const int bid0 = blockIdx.x;
  const int nb = (bid0 & 7) * 576 + (bid0 >> 3);
  const int b = nb / 576;
  const int rem = nb - b * 576;
  const int h = rem / 9;
  const int dy = rem - h * 9;
  const int row2 = h + dy - 4;

  float* outbase = out + (((size_t)b * ND + (size_t)dy * 9) * Hh + h) * Ww;

  if ((unsigned)row2 >= (unsigned)Hh) {  // dy shifts row out of range -> zeros
    if (tid < 144) {
      const int dx = tid >> 4, qq = tid & 15;
      const float4 z = make_float4(0.f, 0.f, 0.f, 0.f);
      *(float4*)(outbase + (size_t)dx * HW + 8 * qq) = z;
      *(float4*)(outbase + (size_t)dx * HW + 8 * qq + 4) = z;
    }
    return;
  }

  const int wb = w * WREG;
  {  // zero the 8 pad floats of each (buf, ch) row: exactly 64 per wave
    const int b2 = lane >> 5, rl = lane & 31, j = rl >> 3, p = rl & 7;
    lds[wb + b2 * WBUF + j * ROWF + (p < 4 ? p : 128 + p)] = 0.0f;
  }

  // parity-deinterleaved per-lane source x (LDS dest is linear; source is
  // pre-swizzled so b128 window reads are 16B-aligned and 2-way-free):
  const int xA = 8 * ((lane + 4) >> 2) + ((lane + 4) & 3) - 4;  // -> phys 4+lane
  const int xB = 8 * (lane >> 2) + (lane & 3);                  // -> phys 68+lane
  const float* in2row = in2 + ((size_t)b * Cc * Hh + row2) * Ww;
  const float* v1p =
      in1 + ((size_t)(b * Cc + 4 * w + cslo) * Hh + h) * Ww + 8 * q;

#define STAGE(P, BUF)                                                   \
  {                                                                     \
    const float* s0_ = in2row + (size_t)(16 * (P) + 4 * w) * HW;        \
    _Pragma("unroll") for (int j_ = 0; j_ < 4; ++j_) {                  \
      const float* src_ = s0_ + (size_t)j_ * HW;                        \
      async4(src_ + xA, &lds[wb + (BUF) * WBUF + j_ * ROWF + 4]);       \
      async4(src_ + xB, &lds[wb + (BUF) * WBUF + j_ * ROWF + 68]);      \
    }                                                                   \
  }

#define LOADV1(P, DST)                                                  \
  {                                                                     \
    const float* pp_ = v1p + (size_t)(16 * (P)) * HW;                   \
    const float4 a_ = *(const float4*)pp_;                              \
    const float4 d_ = *(const float4*)(pp_ + 4);                        \
    DST[0] = a_.x; DST[1] = a_.y; DST[2] = a_.z; DST[3] = a_.w;         \
    DST[4] = d_.x; DST[5] = d_.y; DST[6] = d_.z; DST[7] = d_.w;         \
  }

#define COMPUTE(BUF, V1)                                                 \
  {                                                                      \
    const int br_ = wb + (BUF) * WBUF + cslo * ROWF + 4 * q;             \
    const float4 A_ = *(const float4*)&lds[br_];       /* px 0..3  */    \
    const float4 B_ = *(const float4*)&lds[br_ + 68];  /* px 4..7  */    \
    const float4 C_ = *(const float4*)&lds[br_ + 4];   /* px 8..11 */    \
    const float4 D_ = *(const float4*)&lds[br_ + 72];  /* px 12..15*/    \
    const float t_[16] = {A_.x, A_.y, A_.z, A_.w, B_.x, B_.y, B_.z, B_.w,\
                          C_.x, C_.y, C_.z, C_.w, D_.x, D_.y, D_.z, D_.w};\
    _Pragma("unroll") for (int dx_ = 0; dx_ < 9; ++dx_)                  \
      _Pragma("unroll") for (int px_ = 0; px_ < 8; ++px_)                \
        acc[px_][dx_] = fmaf(V1[px_], t_[px_ + dx_], acc[px_][dx_]);     \
  }

  float acc[8][9];
#pragma unroll
  for (int px = 0; px < 8; ++px)
#pragma unroll
    for (int dx = 0; dx < 9; ++dx) acc[px][dx] = 0.0f;

  float v1a[8], v1b[8];
  STAGE(0, 0);
  LOADV1(0, v1a);

#pragma unroll 1
  for (int pp = 0; pp < NPH; pp += 2) {
    STAGE(pp + 1, 1);
    LOADV1(pp + 1, v1b);
    // drain stage(pp)+v1(pp) (oldest); keep the 10 just issued in flight
    asm volatile("s_waitcnt vmcnt(10)" ::: "memory");
    COMPUTE(0, v1a);
    if (pp + 2 < NPH) {
      STAGE(pp + 2, 0);
      LOADV1(pp + 2, v1a);
      asm volatile("s_waitcnt vmcnt(10)" ::: "memory");
    } else {
      asm volatile("s_waitcnt vmcnt(0)" ::: "memory");
    }
    COMPUTE(1, v1b);
  }

  // reduce the 4 cslo slices within each wave (lanes q, q+16, q+32, q+48)
#pragma unroll
  for (int px = 0; px < 8; ++px)
#pragma unroll
    for (int dx = 0; dx < 9; ++dx) {
      float v = acc[px][dx];
      v += __shfl_xor(v, 16, 64);
      v += __shfl_xor(v, 32, 64);
      acc[px][dx] = v;
    }

  __syncthreads();  // all waves done with staging region before overwrite
  if (cslo == 0) {  // wave partial: lds[((w*16+q)*9+dx)*8+px]
    const int pb = (w * 16 + q) * 72;
#pragma unroll
    for (int dx = 0; dx < 9; ++dx) {
      *(float4*)&lds[pb + dx * 8] =
          make_float4(acc[0][dx], acc[1][dx], acc[2][dx], acc[3][dx]);
      *(float4*)&lds[pb + dx * 8 + 4] =
          make_float4(acc[4][dx], acc[5][dx], acc[6][dx], acc[7][dx]);
    }
  }
  __syncthreads();

  if (tid < 144) {  // sum 4 wave-partials, scale, store
    const int dx = tid >> 4, qq = tid & 15;
    const float s = 1.0f / 256.0f;
    float r[8];
#pragma unroll
    for (int px = 0; px < 8; ++px) r[px] = 0.0f;
#pragma unroll
    for (int w4 = 0; w4 < 4; ++w4) {
      const int pb = ((w4 * 16 + qq) * 9 + dx) * 8;
      const float4 lo = *(const float4*)&lds[pb];
      const float4 hi = *(const float4*)&lds[pb + 4];
      r[0] += lo.x; r[1] += lo.y; r[2] += lo.z; r[3] += lo.w;
      r[4] += hi.x; r[5] += hi.y; r[6] += hi.z; r[7] += hi.w;
    }
    *(float4*)(outbase + (size_t)dx * HW + 8 * qq) =
        make_float4(r[0] * s, r[1] * s, r[2] * s, r[3] * s);
    *(float4*)(outbase + (size_t)dx * HW + 8 * qq + 4) =
        make_float4(r[4] * s, r[5] * s, r[6] * s, r[7] * s);
  }
}

}  // namespace

extern "C" void kernel_launch(void* const* d_in, const int* in_sizes, int n_in,
                              void* d_out, int out_size, void* d_ws,
                              size_t ws_size, hipStream_t stream) {
  (void)in_sizes; (void)n_in; (void)out_size; (void)d_ws; (void)ws_size;
  const float* in1 = (const float*)d_in[0];
  const float* in2 = (const float*)d_in[1];
  float* outp = (float*)d_out;
  corr_kernel<<<4608, 256, 0, stream>>>(in1, in2, outp);
}